// Round 11
// baseline (28.824 us; speedup 1.0000x reference)
//
#include <hip/hip_runtime.h>
#include <math.h>

// Chamfer loss, B=8, N=M=4096, D=3, fp32. Two kernels (r7 skeleton).
// k1: 256 blocks = (dir, batch, 256-query chunk), T=1024 (16 waves, 4/SIMD).
//     Thread (qrow=tid&31, slice=tid>>5): 8 queries, scans 128-target slice.
//     HYBRID target feed (r11): slices 0-15 read a 32 KB LDS stage
//     (ds_read_b128 broadcast, 2 addrs/wave = free); slices 16-31 read
//     targets straight from global (same-addr 12 B broadcast, L2-resident,
//     |t|^2 inline). Halves the LDS-pipe load that was ~86% subscribed
//     against VALU; the two memory pipes run in parallel.
//     d' = |t|^2 - 2 q.t ; v_min3_f32 folds the pair-min (3.5 ops/pair).
//     |q|^2 + clamp deferred past the cross-slice min.
// k2: one wave sums the 256 weighted per-block partials (float4 loads).

constexpr int BATCH = 8;
constexpr int NP    = 4096;   // points per cloud
constexpr int T     = 1024;   // threads per block (16 waves, 4/SIMD)
constexpr int QPB   = 256;    // queries per block
constexpr int KPT   = 8;      // queries per thread
constexpr int S     = 32;     // target slices
constexpr int TPS   = 128;    // targets per slice
constexpr int NTL   = 2048;   // targets staged in LDS (slices 0-15)

__global__ __launch_bounds__(T, 4) void chamfer_main(
    const float* __restrict__ x, const float* __restrict__ y,
    const float* __restrict__ w, float* __restrict__ ps)
{
    const int bid = blockIdx.x;          // dir(1b) | b(3b) | qc(4b)
    const int dir = bid >> 7;
    const int b   = (bid >> 4) & 7;
    const int qc  = bid & 15;

    const float* q = dir ? y : x;
    const float* t = dir ? x : y;

    __shared__ float4 ty[NTL];           // 32 KB target stage (first half)
    __shared__ float  pmin[S / 2][QPB];  // 16 KB cross-slice-pair mins
    __shared__ float  qn[QPB];           // |q|^2 per query
    __shared__ float  rsum[T / 64];

    const int tid = threadIdx.x;

    // stage targets [0, 2048) of batch b (r7 proven pattern:
    // strided scalar global reads + lane-consecutive b128 LDS writes)
    const float* tb = t + (size_t)b * NP * 3;
    for (int j = tid; j < NTL; j += T) {
        float t0 = tb[3 * j + 0];
        float t1 = tb[3 * j + 1];
        float t2 = tb[3 * j + 2];
        ty[j] = make_float4(t0, t1, t2, fmaf(t0, t0, fmaf(t1, t1, t2 * t2)));
    }

    // this thread's 8 queries (24 consecutive floats, 16B-aligned)
    const int qrow  = tid & 31;
    const int slice = tid >> 5;          // [0,32); wave = slices {2w, 2w+1}
    const int n0 = b * NP + qc * QPB + qrow * KPT;
    const float4* qb = reinterpret_cast<const float4*>(q + (size_t)n0 * 3);
    float4 v0 = qb[0], v1 = qb[1], v2 = qb[2], v3 = qb[3], v4 = qb[4], v5 = qb[5];
    float px[KPT][3] = {
        {v0.x, v0.y, v0.z}, {v0.w, v1.x, v1.y},
        {v1.z, v1.w, v2.x}, {v2.y, v2.z, v2.w},
        {v3.x, v3.y, v3.z}, {v3.w, v4.x, v4.y},
        {v4.z, v4.w, v5.x}, {v5.y, v5.z, v5.w},
    };
    float xn[KPT][3], mn[KPT];
    #pragma unroll
    for (int k = 0; k < KPT; ++k) {
        float x2 = fmaf(px[k][0], px[k][0],
                   fmaf(px[k][1], px[k][1], px[k][2] * px[k][2]));
        if (slice == 0) qn[qrow * KPT + k] = x2;
        #pragma unroll
        for (int d = 0; d < 3; ++d) xn[k][d] = -2.0f * px[k][d];
        mn[k] = INFINITY;
    }

    __syncthreads();

    if (slice < 16) {
        // LDS path: min over d' = |t|^2 - 2 q.t from the stage
        const int j0 = slice * TPS;
        #pragma unroll 4
        for (int j = j0; j < j0 + TPS; j += 2) {
            float4 ta = ty[j];           // 2 distinct addrs/wave (free)
            float4 tc = ty[j + 1];
            #pragma unroll
            for (int k = 0; k < KPT; ++k) {
                float da = fmaf(xn[k][0], ta.x,
                           fmaf(xn[k][1], ta.y, fmaf(xn[k][2], ta.z, ta.w)));
                float db = fmaf(xn[k][0], tc.x,
                           fmaf(xn[k][1], tc.y, fmaf(xn[k][2], tc.z, tc.w)));
                float m;
                asm("v_min3_f32 %0, %1, %2, %3"
                    : "=v"(m) : "v"(mn[k]), "v"(da), "v"(db));
                mn[k] = m;               // 3.5 VALU ops per pair
            }
        }
    } else {
        // global path: same-addr 12 B broadcast reads (L2), |t|^2 inline
        const float* gt = tb + (size_t)(slice * TPS) * 3;
        #pragma unroll 4
        for (int i = 0; i < TPS; i += 2) {
            float a0 = gt[3 * i + 0], a1 = gt[3 * i + 1], a2 = gt[3 * i + 2];
            float c0 = gt[3 * i + 3], c1 = gt[3 * i + 4], c2 = gt[3 * i + 5];
            float aw = fmaf(a0, a0, fmaf(a1, a1, a2 * a2));
            float cw = fmaf(c0, c0, fmaf(c1, c1, c2 * c2));
            #pragma unroll
            for (int k = 0; k < KPT; ++k) {
                float da = fmaf(xn[k][0], a0,
                           fmaf(xn[k][1], a1, fmaf(xn[k][2], a2, aw)));
                float db = fmaf(xn[k][0], c0,
                           fmaf(xn[k][1], c1, fmaf(xn[k][2], c2, cw)));
                float m;
                asm("v_min3_f32 %0, %1, %2, %3"
                    : "=v"(m) : "v"(mn[k]), "v"(da), "v"(db));
                mn[k] = m;
            }
        }
    }

    // intra-wave combine of slice pairs (lanes l <-> l+32), then exchange
    #pragma unroll
    for (int k = 0; k < KPT; ++k)
        mn[k] = fminf(mn[k], __shfl_xor(mn[k], 32, 64));
    if ((slice & 1) == 0) {
        #pragma unroll
        for (int k = 0; k < KPT; ++k)
            pmin[slice >> 1][qrow * KPT + k] = mn[k];
    }
    __syncthreads();

    float val = 0.0f;
    if (tid < QPB) {                     // thread tid owns query tid
        float m = pmin[0][tid];
        #pragma unroll
        for (int s = 1; s < S / 2; ++s) m = fminf(m, pmin[s][tid]);
        val = fmaxf(qn[tid] + m, 0.0f);  // clamp after full min
    }

    // fixed-order block sum (other waves contribute 0)
    for (int off = 32; off; off >>= 1) val += __shfl_down(val, off, 64);
    if ((tid & 63) == 0) rsum[tid >> 6] = val;
    __syncthreads();
    if (tid == 0) {
        float s = 0.0f;
        #pragma unroll
        for (int i = 0; i < T / 64; ++i) s += rsum[i];
        ps[bid] = s * w[b] * (1.0f / ((float)NP * (float)BATCH));
    }
}

__global__ __launch_bounds__(64) void chamfer_final(
    const float* __restrict__ ps, float* __restrict__ out)
{
    const int l = threadIdx.x;           // one wave
    float4 v = reinterpret_cast<const float4*>(ps)[l];
    float s = (v.x + v.y) + (v.z + v.w);
    for (int off = 32; off; off >>= 1) s += __shfl_down(s, off, 64);
    if (l == 0) out[0] = s;
}

extern "C" void kernel_launch(void* const* d_in, const int* in_sizes, int n_in,
                              void* d_out, int out_size, void* d_ws, size_t ws_size,
                              hipStream_t stream) {
    const float* x = (const float*)d_in[0];   // (8, 4096, 3)
    const float* y = (const float*)d_in[1];   // (8, 4096, 3)
    const float* w = (const float*)d_in[2];   // (8,)
    float* out = (float*)d_out;
    float* ps  = (float*)d_ws;                // 256 floats

    chamfer_main<<<256, T, 0, stream>>>(x, y, w, ps);
    chamfer_final<<<1, 64, 0, stream>>>(ps, out);
}

// Round 14
// 26.939 us; speedup vs baseline: 1.0700x; 1.0700x over previous
//
#include <hip/hip_runtime.h>
#include <math.h>

// Chamfer loss, B=8, N=M=4096, D=3, fp32. Two kernels (r7, proven 26.9 us).
// k1: 256 blocks = (dir, batch, 256-query chunk), T=1024 (16 waves, 4/SIMD).
//     Full 4096-pt target cloud staged in LDS as (t0,t1,t2,|t|^2) [64 KB].
//     Thread (qrow=tid&31, slice=tid>>5): 8 queries, scans 128-target slice.
//     Wave = 2 slices -> ds_read_b128 has 2 distinct addrs (free, m136).
//     d' = |t|^2 - 2 q.t ; v_min3_f32 folds the pair-min (3.5 ops/pair =
//     the VALU floor: 3 fma per 3D-dot+bias target, half a min3).
//     |q|^2 + clamp deferred past the cross-slice min.
// k2: single block sums the 256 weighted per-block partials.
//
// Session ledger (why this shape):
//   r3  fused finish w/ fences        35.6  (fence storm)
//   r5  full-LDS stage, KPT=8         28.1
//   r6  packed-atomic + memset node   34.4  (memset = full dispatch)
//   r7  T=1024 + v_min3               26.9  <- this kernel
//   r8  cooperative grid.sync         59.5  (sync >> dispatch saved)
//   r9  staged-b128 stage + unroll8   27.6  (LDS write conflicts)
//   r10 KPT=16                        28.4  (reg pressure > read savings)
//   r11 hybrid LDS/global feed        28.8  (L2 broadcast slower)
//   r12/r13 split-bf16 MFMA           failed absmax (slot pairing opaque)

constexpr int BATCH = 8;
constexpr int NP    = 4096;   // points per cloud
constexpr int T     = 1024;   // threads per block (16 waves, 4/SIMD)
constexpr int QPB   = 256;    // queries per block
constexpr int KPT   = 8;      // queries per thread
constexpr int S     = 32;     // target slices (threads per query column)
constexpr int TPS   = 128;    // targets per slice

__global__ __launch_bounds__(T, 4) void chamfer_main(
    const float* __restrict__ x, const float* __restrict__ y,
    const float* __restrict__ w, float* __restrict__ ps)
{
    const int bid = blockIdx.x;          // dir(1b) | b(3b) | qc(4b)
    const int dir = bid >> 7;
    const int b   = (bid >> 4) & 7;
    const int qc  = bid & 15;

    const float* q = dir ? y : x;
    const float* t = dir ? x : y;

    __shared__ float4 ty[NP];            // 64 KB target stage
    __shared__ float  pmin[S / 2][QPB];  // 16 KB cross-slice-pair mins
    __shared__ float  qn[QPB];           // |q|^2 per query
    __shared__ float  rsum[T / 64];

    const int tid = threadIdx.x;

    // stage all 4096 targets of batch b (strided scalar global reads +
    // lane-consecutive b128 LDS writes = conflict-free)
    const float* tb = t + (size_t)b * NP * 3;
    for (int j = tid; j < NP; j += T) {
        float t0 = tb[3 * j + 0];
        float t1 = tb[3 * j + 1];
        float t2 = tb[3 * j + 2];
        ty[j] = make_float4(t0, t1, t2, fmaf(t0, t0, fmaf(t1, t1, t2 * t2)));
    }

    // this thread's 8 queries (24 consecutive floats, 16B-aligned)
    const int qrow  = tid & 31;
    const int slice = tid >> 5;          // [0,32); wave = slices {2w, 2w+1}
    const int n0 = b * NP + qc * QPB + qrow * KPT;
    const float4* qb = reinterpret_cast<const float4*>(q + (size_t)n0 * 3);
    float4 v0 = qb[0], v1 = qb[1], v2 = qb[2], v3 = qb[3], v4 = qb[4], v5 = qb[5];
    float px[KPT][3] = {
        {v0.x, v0.y, v0.z}, {v0.w, v1.x, v1.y},
        {v1.z, v1.w, v2.x}, {v2.y, v2.z, v2.w},
        {v3.x, v3.y, v3.z}, {v3.w, v4.x, v4.y},
        {v4.z, v4.w, v5.x}, {v5.y, v5.z, v5.w},
    };
    float xn[KPT][3], mn[KPT];
    #pragma unroll
    for (int k = 0; k < KPT; ++k) {
        float x2 = fmaf(px[k][0], px[k][0],
                   fmaf(px[k][1], px[k][1], px[k][2] * px[k][2]));
        if (slice == 0) qn[qrow * KPT + k] = x2;
        #pragma unroll
        for (int d = 0; d < 3; ++d) xn[k][d] = -2.0f * px[k][d];
        mn[k] = INFINITY;
    }

    __syncthreads();

    // min over this slice's targets of d' = |t|^2 - 2 q.t
    const int j0 = slice * TPS;
    #pragma unroll 4
    for (int j = j0; j < j0 + TPS; j += 2) {
        float4 ta = ty[j];               // 2 distinct addrs per wave (free)
        float4 tc = ty[j + 1];
        #pragma unroll
        for (int k = 0; k < KPT; ++k) {
            float da = fmaf(xn[k][0], ta.x,
                       fmaf(xn[k][1], ta.y, fmaf(xn[k][2], ta.z, ta.w)));
            float db = fmaf(xn[k][0], tc.x,
                       fmaf(xn[k][1], tc.y, fmaf(xn[k][2], tc.z, tc.w)));
            float m;
            asm("v_min3_f32 %0, %1, %2, %3"
                : "=v"(m) : "v"(mn[k]), "v"(da), "v"(db));
            mn[k] = m;                   // 3.5 VALU ops per pair
        }
    }

    // intra-wave combine of slice pairs (lanes l <-> l+32), then exchange
    #pragma unroll
    for (int k = 0; k < KPT; ++k)
        mn[k] = fminf(mn[k], __shfl_xor(mn[k], 32, 64));
    if ((slice & 1) == 0) {
        #pragma unroll
        for (int k = 0; k < KPT; ++k)
            pmin[slice >> 1][qrow * KPT + k] = mn[k];
    }
    __syncthreads();

    float val = 0.0f;
    if (tid < QPB) {                     // thread tid owns query tid
        float m = pmin[0][tid];
        #pragma unroll
        for (int s = 1; s < S / 2; ++s) m = fminf(m, pmin[s][tid]);
        val = fmaxf(qn[tid] + m, 0.0f);  // clamp after full min
    }

    // fixed-order block sum (other waves contribute 0)
    for (int off = 32; off; off >>= 1) val += __shfl_down(val, off, 64);
    if ((tid & 63) == 0) rsum[tid >> 6] = val;
    __syncthreads();
    if (tid == 0) {
        float s = 0.0f;
        #pragma unroll
        for (int i = 0; i < T / 64; ++i) s += rsum[i];
        ps[bid] = s * w[b] * (1.0f / ((float)NP * (float)BATCH));
    }
}

__global__ __launch_bounds__(256) void chamfer_final(
    const float* __restrict__ ps, float* __restrict__ out)
{
    const int tid = threadIdx.x;         // 256 threads
    float v = ps[tid];
    for (int off = 32; off; off >>= 1) v += __shfl_down(v, off, 64);
    __shared__ float red[4];
    if ((tid & 63) == 0) red[tid >> 6] = v;
    __syncthreads();
    if (tid == 0) out[0] = (red[0] + red[1]) + (red[2] + red[3]);
}

extern "C" void kernel_launch(void* const* d_in, const int* in_sizes, int n_in,
                              void* d_out, int out_size, void* d_ws, size_t ws_size,
                              hipStream_t stream) {
    const float* x = (const float*)d_in[0];   // (8, 4096, 3)
    const float* y = (const float*)d_in[1];   // (8, 4096, 3)
    const float* w = (const float*)d_in[2];   // (8,)
    float* out = (float*)d_out;
    float* ps  = (float*)d_ws;                // 256 floats

    chamfer_main<<<256, T, 0, stream>>>(x, y, w, ps);
    chamfer_final<<<1, 256, 0, stream>>>(ps, out);
}